// Round 1
// baseline (442.263 us; speedup 1.0000x reference)
//
#include <hip/hip_runtime.h>
#include <hip/hip_bf16.h>
#include <stdint.h>

typedef __attribute__((ext_vector_type(4))) int i32x4;

#define QLIM 127.0f
#define BM 128
#define BN 128
#define BK 64

__device__ __forceinline__ int quant_pack4(float4 v, float s) {
    float a0 = rintf(fminf(fmaxf(v.x * s, -QLIM), QLIM));
    float a1 = rintf(fminf(fmaxf(v.y * s, -QLIM), QLIM));
    float a2 = rintf(fminf(fmaxf(v.z * s, -QLIM), QLIM));
    float a3 = rintf(fminf(fmaxf(v.w * s, -QLIM), QLIM));
    return ((int)a0 & 255) | (((int)a1 & 255) << 8) |
           (((int)a2 & 255) << 16) | (((int)a3 & 255) << 24);
}

// fp32 -> int8 per-tensor symmetric quantization, 16 elements per thread-iter.
__global__ void quantize_kernel(const float* __restrict__ in, int4* __restrict__ q,
                                const float* __restrict__ amax, long n16) {
    const float s = QLIM / amax[0];
    const long stride = (long)gridDim.x * blockDim.x;
    for (long i = (long)blockIdx.x * blockDim.x + threadIdx.x; i < n16; i += stride) {
        const float4* p = (const float4*)in + i * 4;
        float4 v0 = p[0], v1 = p[1], v2 = p[2], v3 = p[3];
        int4 r;
        r.x = quant_pack4(v0, s);
        r.y = quant_pack4(v1, s);
        r.z = quant_pack4(v2, s);
        r.w = quant_pack4(v3, s);
        q[i] = r;
    }
}

// int8 GEMM: C[M][N] = A[M][K] * B[N][K]^T, fp32 epilogue (rescale + bias).
// m97-verified 128x128 structure: 4 waves (2x2), each wave owns a 64x64 output
// sub-tile = 4x4 fragments of 16x16, mfma_i32_16x16x64_i8 over BK=64.
__global__ __launch_bounds__(256) void gemm_i8_kernel(
    const signed char* __restrict__ A,   // qx [M][K]
    const signed char* __restrict__ B,   // qw [N][K]
    const float* __restrict__ bias,      // [N]
    const float* __restrict__ amax,
    const float* __restrict__ amax_w,
    float* __restrict__ C,               // [M][N]
    int M, int N, int K)
{
    __shared__ signed char As[BM * BK];  // 8 KB, row-major [128][64]
    __shared__ signed char Bs[BN * BK];  // 8 KB

    const int tid  = threadIdx.x;
    const int wid  = tid >> 6;       // wave 0..3
    const int lane = tid & 63;
    const int wm   = wid >> 1;       // wave row 0..1
    const int wn   = wid & 1;        // wave col 0..1
    const int bm   = blockIdx.y;
    const int bn   = blockIdx.x;

    // staging: thread t covers tile bytes [t*16, t*16+16) per 4KB round
    const int srow = tid >> 2;             // 0..63 (row within 64-row half)
    const int scol = (tid & 3) << 4;       // 0,16,32,48

    const signed char* a_base = A + (size_t)(bm * BM) * K;
    const signed char* b_base = B + (size_t)(bn * BN) * K;

    // fragment addressing: lane l -> row (l&15), k-offset (l>>4)*16, 16 contiguous bytes
    const int fr = lane & 15;
    const int fk = (lane >> 4) << 4;

    i32x4 acc[4][4] = {};

    for (int k0 = 0; k0 < K; k0 += BK) {
#pragma unroll
        for (int j = 0; j < 2; ++j) {
            const signed char* ag = a_base + (size_t)(j * 64 + srow) * K + k0 + scol;
            const signed char* bg = b_base + (size_t)(j * 64 + srow) * K + k0 + scol;
            // LDS dest: wave-uniform base; HW adds lane*16. Linear layout matches
            // row-major [128][64] exactly ((l/4)*64 + (l%4)*16 == l*16).
            __builtin_amdgcn_global_load_lds(
                (const __attribute__((address_space(1))) void*)ag,
                (__attribute__((address_space(3))) void*)(As + j * 4096 + wid * 1024),
                16, 0, 0);
            __builtin_amdgcn_global_load_lds(
                (const __attribute__((address_space(1))) void*)bg,
                (__attribute__((address_space(3))) void*)(Bs + j * 4096 + wid * 1024),
                16, 0, 0);
        }
        __syncthreads();   // compiler emits s_waitcnt vmcnt(0) before barrier

        i32x4 a_frag[4], b_frag[4];
#pragma unroll
        for (int m = 0; m < 4; ++m)
            a_frag[m] = *(const i32x4*)(As + (wm * 64 + m * 16 + fr) * 64 + fk);
#pragma unroll
        for (int n = 0; n < 4; ++n)
            b_frag[n] = *(const i32x4*)(Bs + (wn * 64 + n * 16 + fr) * 64 + fk);

#pragma unroll
        for (int m = 0; m < 4; ++m)
#pragma unroll
            for (int n = 0; n < 4; ++n)
                acc[m][n] = __builtin_amdgcn_mfma_i32_16x16x64_i8(
                    a_frag[m], b_frag[n], acc[m][n], 0, 0, 0);

        __syncthreads();
    }

    // epilogue: out = acc / ((127/amax)*(127/amax_w)) + bias
    const float sa  = QLIM / amax[0];
    const float sw  = QLIM / amax_w[0];
    const float inv = 1.0f / (sa * sw);
    const int row0 = bm * BM + wm * 64;
    const int col0 = bn * BN + wn * 64;
#pragma unroll
    for (int m = 0; m < 4; ++m) {
#pragma unroll
        for (int n = 0; n < 4; ++n) {
            const int colc = col0 + n * 16 + fr;
            const float bv = bias[colc];
#pragma unroll
            for (int r = 0; r < 4; ++r) {
                const int rowc = row0 + m * 16 + ((lane >> 4) << 2) + r;
                C[(size_t)rowc * N + colc] = (float)acc[m][n][r] * inv + bv;
            }
        }
    }
}

extern "C" void kernel_launch(void* const* d_in, const int* in_sizes, int n_in,
                              void* d_out, int out_size, void* d_ws, size_t ws_size,
                              hipStream_t stream) {
    const float* x      = (const float*)d_in[0];
    const float* w      = (const float*)d_in[1];
    const float* bias   = (const float*)d_in[2];
    const float* amax   = (const float*)d_in[3];
    const float* amax_w = (const float*)d_in[4];
    float* out = (float*)d_out;

    const int N = in_sizes[2];                 // 4096
    const int K = in_sizes[1] / N;             // 4096
    const int M = in_sizes[0] / K;             // 8192

    signed char* qx = (signed char*)d_ws;           // M*K bytes (32 MB)
    signed char* qw = qx + (size_t)M * K;           // N*K bytes (16 MB)

    const long nx16 = (long)M * K / 16;
    const long nw16 = (long)N * K / 16;
    quantize_kernel<<<2048, 256, 0, stream>>>(x, (int4*)qx, amax, nx16);
    quantize_kernel<<<1024, 256, 0, stream>>>(w, (int4*)qw, amax_w, nw16);

    dim3 grid(N / BN, M / BM);
    gemm_i8_kernel<<<grid, 256, 0, stream>>>(qx, qw, bias, amax, amax_w, out, M, N, K);
}